// Round 2
// baseline (544.315 us; speedup 1.0000x reference)
//
#include <hip/hip_runtime.h>

// Problem constants
#define M_TOT 8192      // 4 * 2048
#define K_TOT 4096      // IN_FEATURES
#define N_TOT 4096      // OUT_FEATURES
#define RANK  64
#define SCALING 0.25f

typedef __bf16 bf16x8 __attribute__((ext_vector_type(8)));
typedef float floatx4 __attribute__((ext_vector_type(4)));
typedef unsigned short ushort8v __attribute__((ext_vector_type(8)));

static __device__ __forceinline__ unsigned short f32_to_bf16(float f) {
  unsigned int u = __float_as_uint(f);
  u += 0x7FFFu + ((u >> 16) & 1u);   // round-to-nearest-even
  return (unsigned short)(u >> 16);
}

// async global->LDS, 16B per lane. LDS dest is wave-uniform base + lane*16.
static __device__ __forceinline__ void async_ld16(const void* g, void* l) {
  __builtin_amdgcn_global_load_lds(
      (const __attribute__((address_space(1))) unsigned int*)g,
      (__attribute__((address_space(3))) unsigned int*)l, 16, 0, 0);
}

// ---------------- kernel 1: convert x fp32 -> bf16 ----------------
// R3: 32B read / 16B store per thread.
__global__ __launch_bounds__(256) void cvt_x_kernel(const float4* __restrict__ x,
                                                    ushort8v* __restrict__ xb) {
  int i = blockIdx.x * 256 + threadIdx.x;   // grid sized exactly: no bounds check
  float4 v0 = x[2 * i];
  float4 v1 = x[2 * i + 1];
  ushort8v o;
  o[0] = f32_to_bf16(v0.x); o[1] = f32_to_bf16(v0.y);
  o[2] = f32_to_bf16(v0.z); o[3] = f32_to_bf16(v0.w);
  o[4] = f32_to_bf16(v1.x); o[5] = f32_to_bf16(v1.y);
  o[6] = f32_to_bf16(v1.z); o[7] = f32_to_bf16(v1.w);
  xb[i] = o;
}

// ---------------- kernel 2: W_eff = bf16(wq*scale + 0.25*B@A) ----------------
__global__ __launch_bounds__(256) void build_weff_kernel(
    const int* __restrict__ wq, const float* __restrict__ scale_p,
    const float* __restrict__ A, const float* __restrict__ B,
    unsigned short* __restrict__ Weff) {
  __shared__ float Bs[64][65];                 // [o][r], padded
  __shared__ __align__(16) float As[64][64];   // [r][k], unpadded for float4

  const int tid = threadIdx.x;
  const int o0 = blockIdx.y * 64;
  const int k0 = blockIdx.x * 64;
  const float scale = scale_p[0];

  for (int i = tid; i < 64 * 64; i += 256) {
    int o = i >> 6, r = i & 63;
    Bs[o][r] = B[(size_t)(o0 + o) * RANK + r];
  }
  for (int i = tid; i < 64 * 64; i += 256) {
    int r = i >> 6, kk = i & 63;
    As[r][kk] = A[(size_t)r * K_TOT + k0 + kk];
  }
  __syncthreads();

  const int to = tid >> 4;   // 0..15 -> o sub-block (4 rows)
  const int tk = tid & 15;   // 0..15 -> k sub-block (4 contiguous cols)
  float acc[4][4] = {};
#pragma unroll 8
  for (int r = 0; r < RANK; ++r) {
    float bv[4];
#pragma unroll
    for (int a = 0; a < 4; ++a) bv[a] = Bs[to * 4 + a][r];
    floatx4 av = *(const floatx4*)&As[r][tk * 4];
#pragma unroll
    for (int a = 0; a < 4; ++a)
#pragma unroll
      for (int b = 0; b < 4; ++b) acc[a][b] += bv[a] * av[b];
  }
#pragma unroll
  for (int a = 0; a < 4; ++a) {
    const int o = o0 + to * 4 + a;
    const size_t base = (size_t)o * K_TOT + k0 + tk * 4;
    const int4 wv = *(const int4*)(wq + base);
    ushort4 st;
    st.x = f32_to_bf16((float)wv.x * scale + SCALING * acc[a][0]);
    st.y = f32_to_bf16((float)wv.y * scale + SCALING * acc[a][1]);
    st.z = f32_to_bf16((float)wv.z * scale + SCALING * acc[a][2]);
    st.w = f32_to_bf16((float)wv.w * scale + SCALING * acc[a][3]);
    *(ushort4*)(Weff + base) = st;
  }
}

// ---------------- kernel 3: main GEMM, out = Xb @ Weff^T ----------------
// R3: single barrier per phase; NO explicit lgkmcnt(0) before MFMA — the
// compiler's fine-grained per-fragment lgkm waits let the first MFMAs start
// while the tail of the phase's ds_reads drains. A cheap lgkmcnt(0) sits
// AFTER the MFMA cluster (already drained by data deps) to uphold the WAR
// protocol at the phase-end barrier. Read order: B before A in P1 so the
// first MFMA waits on 6/12 in-order lgkm slots, not 10/12.
//
// WAR ledger (1-barrier phases; waves drift only WITHIN a phase):
//   P1 stages A(buf^1)h0 | P1 reads A(buf)qm0,B(buf)01      -> disjoint
//   P2 stages A(buf^1)h1 | P2 reads B(buf)23                -> disjoint
//   P3 stages B(buf)h0   | P3 reads A(buf)qm1               -> disjoint
//   P4 stages B(buf)h1   | P4 reads nothing                 -> safe
// Cross-phase: each wave executes lgkmcnt(0) before its phase-end barrier,
// so all reads of phase P are drained before any wave enters phase P+1.
// RAW on staged tiles: vmcnt(4) + group-end barrier (unchanged from R2).

template <int QM, int QN>
static __device__ __forceinline__ void ph_mfma(floatx4 (&acc)[8][4],
                                               const bf16x8 (&af)[4][2],
                                               const bf16x8 (&bf)[4][2]) {
#pragma unroll
  for (int ii = 0; ii < 4; ++ii)
#pragma unroll
    for (int jj = 0; jj < 2; ++jj) {
      floatx4 c = acc[QM * 4 + ii][QN * 2 + jj];
      c = __builtin_amdgcn_mfma_f32_16x16x32_bf16(af[ii][0], bf[QN * 2 + jj][0], c, 0, 0, 0);
      c = __builtin_amdgcn_mfma_f32_16x16x32_bf16(af[ii][1], bf[QN * 2 + jj][1], c, 0, 0, 0);
      acc[QM * 4 + ii][QN * 2 + jj] = c;
    }
}

__global__ __launch_bounds__(512, 2) void gemm_kernel(
    const unsigned short* __restrict__ Xb,   // [M_TOT][K_TOT] bf16 bits
    const unsigned short* __restrict__ Wb,   // [N_TOT][K_TOT] bf16 bits
    float* __restrict__ out) {               // [M_TOT][N_TOT] fp32
  __shared__ __align__(16) unsigned char smem[131072];

  const int tid = threadIdx.x;
  const int lane = tid & 63;
  const int wave = tid >> 6;   // 0..7
  const int wm = wave >> 2;    // 0..1 -> 128-row half
  const int wn = wave & 3;     // 0..3 -> 64-col quarter

  // XCD-aware swizzle: 512 blocks, 512 % 8 == 0 -> bijective
  const int bid = blockIdx.x;
  const int swz = (bid & 7) * 64 + (bid >> 3);
  const int bM = (swz >> 4) * 256;   // 32 M-blocks
  const int bN = (swz & 15) * 256;   // 16 N-blocks

  // staging source: thread covers 16B; row = tid>>3, chunk = (tid&7)^(row&7)
  const int srow = tid >> 3;                       // 0..63 rows per 8KB issue
  const int scol = ((tid & 7) ^ (srow & 7)) * 8;   // pre-swizzled k offset
  const unsigned short* xs = Xb + (size_t)(bM + srow) * K_TOT + scol;
  const unsigned short* ws = Wb + (size_t)(bN + srow) * K_TOT + scol;

  // ds_read addressing: frag row = (lane&15), logical chunk = ks*4+(lane>>4)
  const int rb = (lane & 15) * 128;
  const int c0 = (((lane >> 4) + 0) ^ (lane & 7)) * 16;
  const int c1 = (((lane >> 4) + 4) ^ (lane & 7)) * 16;
  const int aBase = wm * 16384;
  const int bBase = 32768 + (wn >> 1) * 16384 + (wn & 1) * 8192;

  floatx4 acc[8][4] = {};
  bf16x8 af[4][2], bf[4][2];

#define BAR() asm volatile("s_barrier" ::: "memory")
#define WAIT_LGKM0() asm volatile("s_waitcnt lgkmcnt(0)" ::: "memory")
#define WAIT_VM(N) asm volatile("s_waitcnt vmcnt(" #N ")" ::: "memory")
#define STAGE_A(BUF, H, S, KO)                                              \
  async_ld16(xs + (size_t)((H) * 128 + (S) * 64) * K_TOT + (KO),            \
             smem + (BUF) * 65536 + (H) * 16384 + (S) * 8192 + tid * 16)
#define STAGE_B(BUF, H, S, KO)                                              \
  async_ld16(ws + (size_t)((H) * 128 + (S) * 64) * K_TOT + (KO),            \
             smem + (BUF) * 65536 + 32768 + (H) * 16384 + (S) * 8192 + tid * 16)
#define DSR_A(BUF, QM, II, KS)                                              \
  af[II][KS] = *(const bf16x8*)(smem + (BUF) * 65536 + aBase +              \
                                ((QM) * 4 + (II)) * 2048 + rb + ((KS) ? c1 : c0))
#define DSR_B(BUF, J, KS)                                                   \
  bf[J][KS] = *(const bf16x8*)(smem + (BUF) * 65536 + bBase +               \
                               (J) * 2048 + rb + ((KS) ? c1 : c0))

#define GROUP(BUF, KA, KB)                                                  \
  {                                                                         \
    /* P1: B01 first, then A qm0; stage A-half0 (tile g+1) -> buf^1 */      \
    DSR_B(BUF, 0, 0); DSR_B(BUF, 0, 1);                                     \
    DSR_B(BUF, 1, 0); DSR_B(BUF, 1, 1);                                     \
    DSR_A(BUF, 0, 0, 0); DSR_A(BUF, 0, 0, 1);                               \
    DSR_A(BUF, 0, 1, 0); DSR_A(BUF, 0, 1, 1);                               \
    DSR_A(BUF, 0, 2, 0); DSR_A(BUF, 0, 2, 1);                               \
    DSR_A(BUF, 0, 3, 0); DSR_A(BUF, 0, 3, 1);                               \
    STAGE_A((BUF) ^ 1, 0, 0, KA); STAGE_A((BUF) ^ 1, 0, 1, KA);             \
    __builtin_amdgcn_s_setprio(1);                                          \
    ph_mfma<0, 0>(acc, af, bf);                                             \
    __builtin_amdgcn_s_setprio(0);                                          \
    WAIT_LGKM0(); BAR();                                                    \
    /* P2: B23; stage A-half1 (tile g+1) -> buf^1 */                        \
    DSR_B(BUF, 2, 0); DSR_B(BUF, 2, 1);                                     \
    DSR_B(BUF, 3, 0); DSR_B(BUF, 3, 1);                                     \
    STAGE_A((BUF) ^ 1, 1, 0, KA); STAGE_A((BUF) ^ 1, 1, 1, KA);             \
    __builtin_amdgcn_s_setprio(1);                                          \
    ph_mfma<0, 1>(acc, af, bf);                                             \
    __builtin_amdgcn_s_setprio(0);                                          \
    WAIT_LGKM0(); BAR();                                                    \
    /* P3: A qm1; stage B-half0 (tile g+2) -> buf */                        \
    DSR_A(BUF, 1, 0, 0); DSR_A(BUF, 1, 0, 1);                               \
    DSR_A(BUF, 1, 1, 0); DSR_A(BUF, 1, 1, 1);                               \
    DSR_A(BUF, 1, 2, 0); DSR_A(BUF, 1, 2, 1);                               \
    DSR_A(BUF, 1, 3, 0); DSR_A(BUF, 1, 3, 1);                               \
    STAGE_B(BUF, 0, 0, KB); STAGE_B(BUF, 0, 1, KB);                         \
    __builtin_amdgcn_s_setprio(1);                                          \
    ph_mfma<1, 1>(acc, af, bf);                                             \
    __builtin_amdgcn_s_setprio(0);                                          \
    WAIT_LGKM0(); BAR();                                                    \
    /* P4: no reads; stage B-half1 (tile g+2); counted vmcnt, NOT 0 */      \
    STAGE_B(BUF, 1, 0, KB); STAGE_B(BUF, 1, 1, KB);                         \
    __builtin_amdgcn_s_setprio(1);                                          \
    ph_mfma<1, 0>(acc, af, bf);                                             \
    __builtin_amdgcn_s_setprio(0);                                          \
    WAIT_VM(4);                                                             \
    BAR();                                                                  \
  }

  // prologue: tile0 (A+B) -> buf0, tile1 B-halves -> buf1; drain once.
  STAGE_A(0, 0, 0, 0); STAGE_A(0, 0, 1, 0);
  STAGE_A(0, 1, 0, 0); STAGE_A(0, 1, 1, 0);
  STAGE_B(0, 0, 0, 0); STAGE_B(0, 0, 1, 0);
  STAGE_B(0, 1, 0, 0); STAGE_B(0, 1, 1, 0);
  STAGE_B(1, 0, 0, 64); STAGE_B(1, 0, 1, 64);
  STAGE_B(1, 1, 0, 64); STAGE_B(1, 1, 1, 64);
  WAIT_VM(0);
  BAR();

  // 64 K-tiles, 2 per iteration (compile-time buffer indices). Stage targets
  // wrap with &63 (redundant but harmless — never read).
  for (int kt = 0; kt < 64; kt += 2) {
    const int ka0 = ((kt + 1) & 63) * 64;   // A of tile kt+1 -> buf1
    const int kb0 = ((kt + 2) & 63) * 64;   // B of tile kt+2 -> buf0
    const int ka1 = ((kt + 2) & 63) * 64;   // A of tile kt+2 -> buf0
    const int kb1 = ((kt + 3) & 63) * 64;   // B of tile kt+3 -> buf1
    GROUP(0, ka0, kb0);
    GROUP(1, ka1, kb1);
  }
  WAIT_VM(0);   // drain tail stages before workgroup exit

  // epilogue: C(i,j,r): row = bM+wm*128+i*16+(lane>>4)*4+r, col = bN+wn*64+j*16+(lane&15)
  const int row0 = bM + wm * 128 + ((lane >> 4) << 2);
  const int col0 = bN + wn * 64 + (lane & 15);
#pragma unroll
  for (int i = 0; i < 8; ++i) {
#pragma unroll
    for (int j = 0; j < 4; ++j) {
#pragma unroll
      for (int r = 0; r < 4; ++r) {
        out[(size_t)(row0 + i * 16 + r) * N_TOT + (col0 + j * 16)] = acc[i][j][r];
      }
    }
  }
#undef BAR
#undef WAIT_LGKM0
#undef WAIT_VM
#undef STAGE_A
#undef STAGE_B
#undef DSR_A
#undef DSR_B
#undef GROUP
}

extern "C" void kernel_launch(void* const* d_in, const int* in_sizes, int n_in,
                              void* d_out, int out_size, void* d_ws, size_t ws_size,
                              hipStream_t stream) {
  const float* x      = (const float*)d_in[0];   // [4,2048,4096] fp32
  const int*   wq     = (const int*)d_in[1];     // [4096,4096] int
  const float* wscale = (const float*)d_in[2];   // [1] fp32
  const float* lora_A = (const float*)d_in[3];   // [64,4096] fp32
  const float* lora_B = (const float*)d_in[4];   // [4096,64] fp32
  float* out = (float*)d_out;

  unsigned short* xb   = (unsigned short*)d_ws;
  unsigned short* weff = (unsigned short*)((char*)d_ws + (size_t)M_TOT * K_TOT * 2);

  cvt_x_kernel<<<16384, 256, 0, stream>>>((const float4*)x, (ushort8v*)xb);
  build_weff_kernel<<<dim3(K_TOT / 64, N_TOT / 64), 256, 0, stream>>>(
      wq, wscale, lora_A, lora_B, weff);
  gemm_kernel<<<512, 512, 0, stream>>>(xb, weff, out);
}

// Round 3
// 525.934 us; speedup vs baseline: 1.0350x; 1.0350x over previous
//
#include <hip/hip_runtime.h>

// Problem constants
#define M_TOT 8192      // 4 * 2048
#define K_TOT 4096      // IN_FEATURES
#define N_TOT 4096      // OUT_FEATURES
#define RANK  64
#define SCALING 0.25f

typedef __bf16 bf16x8 __attribute__((ext_vector_type(8)));
typedef float floatx4 __attribute__((ext_vector_type(4)));
typedef float floatx16 __attribute__((ext_vector_type(16)));
typedef unsigned short ushort8v __attribute__((ext_vector_type(8)));

static __device__ __forceinline__ unsigned short f32_to_bf16(float f) {
  unsigned int u = __float_as_uint(f);
  u += 0x7FFFu + ((u >> 16) & 1u);   // round-to-nearest-even
  return (unsigned short)(u >> 16);
}

// async global->LDS, 16B per lane. LDS dest is wave-uniform base + lane*16.
static __device__ __forceinline__ void async_ld16(const void* g, void* l) {
  __builtin_amdgcn_global_load_lds(
      (const __attribute__((address_space(1))) unsigned int*)g,
      (__attribute__((address_space(3))) unsigned int*)l, 16, 0, 0);
}

// ---------------- kernel 1: convert x fp32 -> bf16 ----------------
__global__ __launch_bounds__(256) void cvt_x_kernel(const float4* __restrict__ x,
                                                    ushort8v* __restrict__ xb) {
  int i = blockIdx.x * 256 + threadIdx.x;   // grid sized exactly: no bounds check
  float4 v0 = x[2 * i];
  float4 v1 = x[2 * i + 1];
  ushort8v o;
  o[0] = f32_to_bf16(v0.x); o[1] = f32_to_bf16(v0.y);
  o[2] = f32_to_bf16(v0.z); o[3] = f32_to_bf16(v0.w);
  o[4] = f32_to_bf16(v1.x); o[5] = f32_to_bf16(v1.y);
  o[6] = f32_to_bf16(v1.z); o[7] = f32_to_bf16(v1.w);
  xb[i] = o;
}

// ---------------- kernel 2: W_eff = bf16(wq*scale + 0.25*B@A) ----------------
// R3 rewrite: was LDS-throughput-bound (~2250 LDS cyc/wave from 4 scalar
// Bs[o][r] column reads per r-iter x 64 waves/CU ~ 60us). Now: 128x128 tile,
// B staged TRANSPOSED (Bts[r][o]) so both operands read as float4; 8x8
// register blocking -> 4 b128 per 64 FMAs (was 2 per 16 + scalars).
__global__ __launch_bounds__(256) void build_weff_kernel(
    const int* __restrict__ wq, const float* __restrict__ scale_p,
    const float* __restrict__ A, const float* __restrict__ B,
    unsigned short* __restrict__ Weff) {
  __shared__ __align__(16) float Bts[64][128];   // [r][o] transposed, 32 KB
  __shared__ __align__(16) float As_[64][128];   // [r][k], 32 KB

  const int tid = threadIdx.x;
  const int bo = blockIdx.y * 128;
  const int bk = blockIdx.x * 128;
  const float scale = scale_p[0];

  // stage B transposed: thread t covers o = t>>1, r-half = t&1 (32 r values).
  // reads are float4 along r (coalesced); writes scalar, 2-way bank alias (free).
  {
    const int o = tid >> 1;
    const int rh = (tid & 1) * 32;
    const float* gb = B + (size_t)(bo + o) * RANK + rh;
#pragma unroll
    for (int j = 0; j < 8; ++j) {
      float4 v = *(const float4*)(gb + j * 4);
      Bts[rh + j * 4 + 0][o] = v.x;
      Bts[rh + j * 4 + 1][o] = v.y;
      Bts[rh + j * 4 + 2][o] = v.z;
      Bts[rh + j * 4 + 3][o] = v.w;
    }
  }
  // stage A linear: 8192 floats, 8 float4 per thread, coalesced both sides.
#pragma unroll
  for (int j = 0; j < 8; ++j) {
    const int ii = j * 1024 + tid * 4;        // float4-aligned flat index
    const int r = ii >> 7, c = ii & 127;
    *(floatx4*)&As_[r][c] = *(const floatx4*)(A + (size_t)r * K_TOT + bk + c);
  }
  __syncthreads();

  const int to = tid >> 4;   // 0..15 -> 8 o-rows
  const int tk = tid & 15;   // 0..15 -> 8 k-cols
  float acc[8][8] = {};
#pragma unroll 4
  for (int r = 0; r < RANK; ++r) {
    floatx4 b0 = *(const floatx4*)&Bts[r][to * 8];
    floatx4 b1 = *(const floatx4*)&Bts[r][to * 8 + 4];
    floatx4 a0 = *(const floatx4*)&As_[r][tk * 8];
    floatx4 a1 = *(const floatx4*)&As_[r][tk * 8 + 4];
    float bv[8] = {b0.x, b0.y, b0.z, b0.w, b1.x, b1.y, b1.z, b1.w};
    float av[8] = {a0.x, a0.y, a0.z, a0.w, a1.x, a1.y, a1.z, a1.w};
#pragma unroll
    for (int a = 0; a < 8; ++a)
#pragma unroll
      for (int b = 0; b < 8; ++b) acc[a][b] += bv[a] * av[b];
  }

#pragma unroll
  for (int a = 0; a < 8; ++a) {
    const int o = bo + to * 8 + a;
    const size_t base = (size_t)o * K_TOT + bk + tk * 8;
    const int4 w0 = *(const int4*)(wq + base);
    const int4 w1 = *(const int4*)(wq + base + 4);
    ushort8v st;
    st[0] = f32_to_bf16((float)w0.x * scale + SCALING * acc[a][0]);
    st[1] = f32_to_bf16((float)w0.y * scale + SCALING * acc[a][1]);
    st[2] = f32_to_bf16((float)w0.z * scale + SCALING * acc[a][2]);
    st[3] = f32_to_bf16((float)w0.w * scale + SCALING * acc[a][3]);
    st[4] = f32_to_bf16((float)w1.x * scale + SCALING * acc[a][4]);
    st[5] = f32_to_bf16((float)w1.y * scale + SCALING * acc[a][5]);
    st[6] = f32_to_bf16((float)w1.z * scale + SCALING * acc[a][6]);
    st[7] = f32_to_bf16((float)w1.w * scale + SCALING * acc[a][7]);
    *(ushort8v*)(Weff + base) = st;
  }
}

// ---------------- kernel 3: main GEMM, out = Xb @ Weff^T ----------------
// R3: switch 16x16x32 -> 32x32x16 MFMA (measured pipe: 2495 vs 2075 TF,
// ~17% faster; halves MFMA instruction count -> more issue slots for
// ds_read). Same staging/swizzle; per-wave tile 128x64 = 4x2 tiles of 32x32.
// Fragments: A/B row = lane&31, k-chunk(16B) = lane>>5; swizzle XOR (lane&7)
// unchanged (row&7 == lane&7). B frags for the whole K-tile are loaded in
// P1/P2 and REUSED in P3/P4 (register reuse halves B LDS reads... total
// reads stay 24/wave/K-tile: A 16 + B 8). Phases: P1 8rd/8mfma, P2 8/8,
// P3 4/8, P4 4/8. Stage + vmcnt(4) ledger identical to R2.
__global__ __launch_bounds__(512, 2) void gemm_kernel(
    const unsigned short* __restrict__ Xb,   // [M_TOT][K_TOT] bf16 bits
    const unsigned short* __restrict__ Wb,   // [N_TOT][K_TOT] bf16 bits
    float* __restrict__ out) {               // [M_TOT][N_TOT] fp32
  __shared__ __align__(16) unsigned char smem[131072];

  const int tid = threadIdx.x;
  const int lane = tid & 63;
  const int wave = tid >> 6;   // 0..7
  const int wm = wave >> 2;    // 0..1 -> 128-row half
  const int wn = wave & 3;     // 0..3 -> 64-col quarter

  // XCD-aware swizzle: 512 blocks, 512 % 8 == 0 -> bijective
  const int bid = blockIdx.x;
  const int swz = (bid & 7) * 64 + (bid >> 3);
  const int bM = (swz >> 4) * 256;   // 32 M-blocks
  const int bN = (swz & 15) * 256;   // 16 N-blocks

  // staging source: thread covers 16B; row = tid>>3, chunk = (tid&7)^(row&7)
  const int srow = tid >> 3;                       // 0..63 rows per 8KB issue
  const int scol = ((tid & 7) ^ (srow & 7)) * 8;   // pre-swizzled k offset
  const unsigned short* xs = Xb + (size_t)(bM + srow) * K_TOT + scol;
  const unsigned short* ws = Wb + (size_t)(bN + srow) * K_TOT + scol;

  // ds_read addressing: row = lane&31 (128B rows), logical chunk = ks*2+hi
  const int hi = lane >> 5;
  const int l7 = lane & 7;
  const int rb = (lane & 31) * 128;
  const int cc0 = ((0 * 2 + hi) ^ l7) * 16;
  const int cc1 = ((1 * 2 + hi) ^ l7) * 16;
  const int cc2 = ((2 * 2 + hi) ^ l7) * 16;
  const int cc3 = ((3 * 2 + hi) ^ l7) * 16;
  const int aBase = wm * 16384;          // wave's 128-row A half
  const int bBase = 32768 + wn * 8192;   // wave's 64-row B quarter

  floatx16 acc[4][2] = {};
  bf16x8 af[2][2];   // [m-slot][k-slot], reloaded each phase
  bf16x8 bf[2][4];   // [n][ks], loaded P1/P2, reused P3/P4

#define BAR() asm volatile("s_barrier" ::: "memory")
#define WAIT_LGKM0() asm volatile("s_waitcnt lgkmcnt(0)" ::: "memory")
#define WAIT_VM(N) asm volatile("s_waitcnt vmcnt(" #N ")" ::: "memory")
#define STAGE_A(BUF, H, S, KO)                                              \
  async_ld16(xs + (size_t)((H) * 128 + (S) * 64) * K_TOT + (KO),            \
             smem + (BUF) * 65536 + (H) * 16384 + (S) * 8192 + tid * 16)
#define STAGE_B(BUF, H, S, KO)                                              \
  async_ld16(ws + (size_t)((H) * 128 + (S) * 64) * K_TOT + (KO),            \
             smem + (BUF) * 65536 + 32768 + (H) * 16384 + (S) * 8192 + tid * 16)
#define RD_A(BUF, MI, MM, KK, CC)                                           \
  af[MM][KK] = *(const bf16x8*)(smem + (BUF) * 65536 + aBase + (MI) * 4096 + rb + (CC))
#define RD_B(BUF, NJ, KS, CC)                                               \
  bf[NJ][KS] = *(const bf16x8*)(smem + (BUF) * 65536 + bBase + (NJ) * 4096 + rb + (CC))

#define MFMA_OCT(MB, PB)                                                    \
  {                                                                         \
    _Pragma("unroll") for (int kk = 0; kk < 2; ++kk)                        \
    _Pragma("unroll") for (int mm = 0; mm < 2; ++mm)                        \
    _Pragma("unroll") for (int nn = 0; nn < 2; ++nn)                        \
      acc[(MB) + mm][nn] = __builtin_amdgcn_mfma_f32_32x32x16_bf16(         \
          af[mm][kk], bf[nn][kk + (PB)], acc[(MB) + mm][nn], 0, 0, 0);      \
  }

#define GROUP(BUF, KA, KB)                                                  \
  {                                                                         \
    /* P1: B ks01 + A m01 ks01; stage A(buf^1) h0 */                        \
    RD_B(BUF, 0, 0, cc0); RD_B(BUF, 1, 0, cc0);                             \
    RD_A(BUF, 0, 0, 0, cc0); RD_A(BUF, 1, 1, 0, cc0);                       \
    RD_B(BUF, 0, 1, cc1); RD_B(BUF, 1, 1, cc1);                             \
    RD_A(BUF, 0, 0, 1, cc1); RD_A(BUF, 1, 1, 1, cc1);                       \
    STAGE_A((BUF) ^ 1, 0, 0, KA); STAGE_A((BUF) ^ 1, 0, 1, KA);             \
    __builtin_amdgcn_s_setprio(1);                                          \
    MFMA_OCT(0, 0);                                                         \
    __builtin_amdgcn_s_setprio(0);                                          \
    WAIT_LGKM0(); BAR();                                                    \
    /* P2: B ks23 + A m01 ks23; stage A(buf^1) h1 */                        \
    RD_B(BUF, 0, 2, cc2); RD_B(BUF, 1, 2, cc2);                             \
    RD_A(BUF, 0, 0, 0, cc2); RD_A(BUF, 1, 1, 0, cc2);                       \
    RD_B(BUF, 0, 3, cc3); RD_B(BUF, 1, 3, cc3);                             \
    RD_A(BUF, 0, 0, 1, cc3); RD_A(BUF, 1, 1, 1, cc3);                       \
    STAGE_A((BUF) ^ 1, 1, 0, KA); STAGE_A((BUF) ^ 1, 1, 1, KA);             \
    __builtin_amdgcn_s_setprio(1);                                          \
    MFMA_OCT(0, 2);                                                         \
    __builtin_amdgcn_s_setprio(0);                                          \
    WAIT_LGKM0(); BAR();                                                    \
    /* P3: A m23 ks01 (B regs reused); stage B(buf) h0 (B LDS drained P2) */ \
    RD_A(BUF, 2, 0, 0, cc0); RD_A(BUF, 3, 1, 0, cc0);                       \
    RD_A(BUF, 2, 0, 1, cc1); RD_A(BUF, 3, 1, 1, cc1);                       \
    STAGE_B(BUF, 0, 0, KB); STAGE_B(BUF, 0, 1, KB);                         \
    __builtin_amdgcn_s_setprio(1);                                          \
    MFMA_OCT(2, 0);                                                         \
    __builtin_amdgcn_s_setprio(0);                                          \
    WAIT_LGKM0(); BAR();                                                    \
    /* P4: A m23 ks23; stage B(buf) h1; counted vmcnt, NOT 0 */             \
    RD_A(BUF, 2, 0, 0, cc2); RD_A(BUF, 3, 1, 0, cc2);                       \
    RD_A(BUF, 2, 0, 1, cc3); RD_A(BUF, 3, 1, 1, cc3);                       \
    STAGE_B(BUF, 1, 0, KB); STAGE_B(BUF, 1, 1, KB);                         \
    __builtin_amdgcn_s_setprio(1);                                          \
    MFMA_OCT(2, 2);                                                         \
    __builtin_amdgcn_s_setprio(0);                                          \
    WAIT_VM(4);                                                             \
    BAR();                                                                  \
  }

  // prologue: tile0 (A+B) -> buf0, tile1 B-halves -> buf1; drain once.
  STAGE_A(0, 0, 0, 0); STAGE_A(0, 0, 1, 0);
  STAGE_A(0, 1, 0, 0); STAGE_A(0, 1, 1, 0);
  STAGE_B(0, 0, 0, 0); STAGE_B(0, 0, 1, 0);
  STAGE_B(0, 1, 0, 0); STAGE_B(0, 1, 1, 0);
  STAGE_B(1, 0, 0, 64); STAGE_B(1, 0, 1, 64);
  STAGE_B(1, 1, 0, 64); STAGE_B(1, 1, 1, 64);
  WAIT_VM(0);
  BAR();

  // 64 K-tiles, 2 per iteration. Tail stages (&63 wrap) are never read.
  for (int kt = 0; kt < 64; kt += 2) {
    const int ka0 = ((kt + 1) & 63) * 64;   // A of tile kt+1 -> buf1
    const int kb0 = ((kt + 2) & 63) * 64;   // B of tile kt+2 -> buf0
    const int ka1 = ((kt + 2) & 63) * 64;   // A of tile kt+2 -> buf0
    const int kb1 = ((kt + 3) & 63) * 64;   // B of tile kt+3 -> buf1
    GROUP(0, ka0, kb0);
    GROUP(1, ka1, kb1);
  }
  WAIT_VM(0);   // drain tail stages before workgroup exit

  // epilogue: 32x32 C/D: col = lane&31, row = (reg&3) + 8*(reg>>2) + 4*hi
  const int col0 = bN + wn * 64 + (lane & 31);
#pragma unroll
  for (int mi = 0; mi < 4; ++mi) {
    const int rbase = bM + wm * 128 + mi * 32 + hi * 4;
#pragma unroll
    for (int nj = 0; nj < 2; ++nj) {
#pragma unroll
      for (int rg = 0; rg < 4; ++rg)
#pragma unroll
        for (int rr = 0; rr < 4; ++rr)
          out[(size_t)(rbase + rg * 8 + rr) * N_TOT + (col0 + nj * 32)] =
              acc[mi][nj][rg * 4 + rr];
    }
  }
#undef BAR
#undef WAIT_LGKM0
#undef WAIT_VM
#undef STAGE_A
#undef STAGE_B
#undef RD_A
#undef RD_B
#undef MFMA_OCT
#undef GROUP
}

extern "C" void kernel_launch(void* const* d_in, const int* in_sizes, int n_in,
                              void* d_out, int out_size, void* d_ws, size_t ws_size,
                              hipStream_t stream) {
  const float* x      = (const float*)d_in[0];   // [4,2048,4096] fp32
  const int*   wq     = (const int*)d_in[1];     // [4096,4096] int
  const float* wscale = (const float*)d_in[2];   // [1] fp32
  const float* lora_A = (const float*)d_in[3];   // [64,4096] fp32
  const float* lora_B = (const float*)d_in[4];   // [4096,64] fp32
  float* out = (float*)d_out;

  unsigned short* xb   = (unsigned short*)d_ws;
  unsigned short* weff = (unsigned short*)((char*)d_ws + (size_t)M_TOT * K_TOT * 2);

  cvt_x_kernel<<<16384, 256, 0, stream>>>((const float4*)x, (ushort8v*)xb);
  build_weff_kernel<<<dim3(K_TOT / 128, N_TOT / 128), 256, 0, stream>>>(
      wq, wscale, lora_A, lora_B, weff);
  gemm_kernel<<<512, 512, 0, stream>>>(xb, weff, out);
}

// Round 4
// 496.141 us; speedup vs baseline: 1.0971x; 1.0600x over previous
//
#include <hip/hip_runtime.h>

// Problem constants
#define M_TOT 8192      // 4 * 2048
#define K_TOT 4096      // IN_FEATURES
#define N_TOT 4096      // OUT_FEATURES
#define RANK  64
#define SCALING 0.25f

typedef __bf16 bf16x8 __attribute__((ext_vector_type(8)));
typedef float floatx4 __attribute__((ext_vector_type(4)));
typedef unsigned short ushort8v __attribute__((ext_vector_type(8)));

static __device__ __forceinline__ unsigned short f32_to_bf16(float f) {
  unsigned int u = __float_as_uint(f);
  u += 0x7FFFu + ((u >> 16) & 1u);   // round-to-nearest-even
  return (unsigned short)(u >> 16);
}

// async global->LDS, 16B per lane. LDS dest is wave-uniform base + lane*16.
static __device__ __forceinline__ void async_ld16(const void* g, void* l) {
  __builtin_amdgcn_global_load_lds(
      (const __attribute__((address_space(1))) unsigned int*)g,
      (__attribute__((address_space(3))) unsigned int*)l, 16, 0, 0);
}

// ---------------- kernel 1: convert x fp32 -> bf16 ----------------
__global__ __launch_bounds__(256) void cvt_x_kernel(const float4* __restrict__ x,
                                                    ushort8v* __restrict__ xb) {
  int i = blockIdx.x * 256 + threadIdx.x;   // grid sized exactly: no bounds check
  float4 v0 = x[2 * i];
  float4 v1 = x[2 * i + 1];
  ushort8v o;
  o[0] = f32_to_bf16(v0.x); o[1] = f32_to_bf16(v0.y);
  o[2] = f32_to_bf16(v0.z); o[3] = f32_to_bf16(v0.w);
  o[4] = f32_to_bf16(v1.x); o[5] = f32_to_bf16(v1.y);
  o[6] = f32_to_bf16(v1.z); o[7] = f32_to_bf16(v1.w);
  xb[i] = o;
}

// ---------------- kernel 2: W_eff = bf16(wq*scale + 0.25*B@A) ----------------
// R3 version (kept): 128x128 tile, B staged transposed, 8x8 register blocking,
// all LDS reads are float4. Non-gemm time dropped ~30us with this.
__global__ __launch_bounds__(256) void build_weff_kernel(
    const int* __restrict__ wq, const float* __restrict__ scale_p,
    const float* __restrict__ A, const float* __restrict__ B,
    unsigned short* __restrict__ Weff) {
  __shared__ __align__(16) float Bts[64][128];   // [r][o] transposed, 32 KB
  __shared__ __align__(16) float As_[64][128];   // [r][k], 32 KB

  const int tid = threadIdx.x;
  const int bo = blockIdx.y * 128;
  const int bk = blockIdx.x * 128;
  const float scale = scale_p[0];

  {
    const int o = tid >> 1;
    const int rh = (tid & 1) * 32;
    const float* gb = B + (size_t)(bo + o) * RANK + rh;
#pragma unroll
    for (int j = 0; j < 8; ++j) {
      float4 v = *(const float4*)(gb + j * 4);
      Bts[rh + j * 4 + 0][o] = v.x;
      Bts[rh + j * 4 + 1][o] = v.y;
      Bts[rh + j * 4 + 2][o] = v.z;
      Bts[rh + j * 4 + 3][o] = v.w;
    }
  }
#pragma unroll
  for (int j = 0; j < 8; ++j) {
    const int ii = j * 1024 + tid * 4;        // float4-aligned flat index
    const int r = ii >> 7, c = ii & 127;
    *(floatx4*)&As_[r][c] = *(const floatx4*)(A + (size_t)r * K_TOT + bk + c);
  }
  __syncthreads();

  const int to = tid >> 4;   // 0..15 -> 8 o-rows
  const int tk = tid & 15;   // 0..15 -> 8 k-cols
  float acc[8][8] = {};
#pragma unroll 4
  for (int r = 0; r < RANK; ++r) {
    floatx4 b0 = *(const floatx4*)&Bts[r][to * 8];
    floatx4 b1 = *(const floatx4*)&Bts[r][to * 8 + 4];
    floatx4 a0 = *(const floatx4*)&As_[r][tk * 8];
    floatx4 a1 = *(const floatx4*)&As_[r][tk * 8 + 4];
    float bv[8] = {b0.x, b0.y, b0.z, b0.w, b1.x, b1.y, b1.z, b1.w};
    float av[8] = {a0.x, a0.y, a0.z, a0.w, a1.x, a1.y, a1.z, a1.w};
#pragma unroll
    for (int a = 0; a < 8; ++a)
#pragma unroll
      for (int b = 0; b < 8; ++b) acc[a][b] += bv[a] * av[b];
  }

#pragma unroll
  for (int a = 0; a < 8; ++a) {
    const int o = bo + to * 8 + a;
    const size_t base = (size_t)o * K_TOT + bk + tk * 8;
    const int4 w0 = *(const int4*)(wq + base);
    const int4 w1 = *(const int4*)(wq + base + 4);
    ushort8v st;
    st[0] = f32_to_bf16((float)w0.x * scale + SCALING * acc[a][0]);
    st[1] = f32_to_bf16((float)w0.y * scale + SCALING * acc[a][1]);
    st[2] = f32_to_bf16((float)w0.z * scale + SCALING * acc[a][2]);
    st[3] = f32_to_bf16((float)w0.w * scale + SCALING * acc[a][3]);
    st[4] = f32_to_bf16((float)w1.x * scale + SCALING * acc[a][4]);
    st[5] = f32_to_bf16((float)w1.y * scale + SCALING * acc[a][5]);
    st[6] = f32_to_bf16((float)w1.z * scale + SCALING * acc[a][6]);
    st[7] = f32_to_bf16((float)w1.w * scale + SCALING * acc[a][7]);
    *(ushort8v*)(Weff + base) = st;
  }
}

// ---------------- kernel 3: main GEMM, out = Xb @ Weff^T ----------------
// R4: back to the proven 16x16x32 MFMA + 16-row conflict-free read pattern
// (R3's 32-row pattern hit 2.5e7 bank-conflict cycles). Structural change:
// TWO phases per K-tile instead of four (2 barriers, not 4) to let the LDS
// pipe (~2300 cyc/K-tile) overlap the MFMA pipe (~2480 cyc/K-tile) instead
// of alternating in lockstep.
//   alpha: stage A(tile g+1)->buf^1 (4 glds); read B all 8 + A qm0 8;
//          MFMA qm0 (32); lgkmcnt(0); BAR.
//   beta : stage B(tile g+2)->buf  (4 glds; B reads drained at alpha-bar);
//          read A qm1 8 (B frags reused from regs); MFMA qm1 (32);
//          lgkmcnt(0); vmcnt(4); BAR.
// WAR: A(buf^1) last read in group g-1 (group-end barrier separates);
//      B(buf) last read in alpha (alpha barrier separates).
// RAW: vmcnt(4) at group end leaves only this group's 4 B-stages in flight
//      => tile g+1 (A staged in alpha, B staged a group earlier) resident.

template <int QM>
static __device__ __forceinline__ void mfma_half(floatx4 (&acc)[8][4],
                                                 const bf16x8 (&af)[4][2],
                                                 const bf16x8 (&bf)[4][2]) {
#pragma unroll
  for (int ks = 0; ks < 2; ++ks)
#pragma unroll
    for (int i = 0; i < 4; ++i)
#pragma unroll
      for (int j = 0; j < 4; ++j)
        acc[QM * 4 + i][j] = __builtin_amdgcn_mfma_f32_16x16x32_bf16(
            af[i][ks], bf[j][ks], acc[QM * 4 + i][j], 0, 0, 0);
}

__global__ __launch_bounds__(512, 2) void gemm_kernel(
    const unsigned short* __restrict__ Xb,   // [M_TOT][K_TOT] bf16 bits
    const unsigned short* __restrict__ Wb,   // [N_TOT][K_TOT] bf16 bits
    float* __restrict__ out) {               // [M_TOT][N_TOT] fp32
  __shared__ __align__(16) unsigned char smem[131072];

  const int tid = threadIdx.x;
  const int lane = tid & 63;
  const int wave = tid >> 6;   // 0..7
  const int wm = wave >> 2;    // 0..1 -> 128-row half
  const int wn = wave & 3;     // 0..3 -> 64-col quarter

  // XCD-aware swizzle: 512 blocks, 512 % 8 == 0 -> bijective
  const int bid = blockIdx.x;
  const int swz = (bid & 7) * 64 + (bid >> 3);
  const int bM = (swz >> 4) * 256;   // 32 M-blocks
  const int bN = (swz & 15) * 256;   // 16 N-blocks

  // staging source: thread covers 16B; row = tid>>3, chunk = (tid&7)^(row&7)
  const int srow = tid >> 3;                       // 0..63 rows per 8KB issue
  const int scol = ((tid & 7) ^ (srow & 7)) * 8;   // pre-swizzled k offset
  const unsigned short* xs = Xb + (size_t)(bM + srow) * K_TOT + scol;
  const unsigned short* ws = Wb + (size_t)(bN + srow) * K_TOT + scol;

  // ds_read addressing (16-row pattern, proven 0-conflict):
  // frag row = lane&15, logical chunk = ks*4 + (lane>>4), phys = log ^ (lane&7)
  const int rb = (lane & 15) * 128;
  const int c0 = (((lane >> 4) + 0) ^ (lane & 7)) * 16;
  const int c1 = (((lane >> 4) + 4) ^ (lane & 7)) * 16;
  const int aBase = wm * 16384;
  const int bBase = 32768 + wn * 8192;

  floatx4 acc[8][4] = {};
  bf16x8 af[4][2];   // A frags for current qm (reloaded alpha/beta)
  bf16x8 bf[4][2];   // B frags, loaded in alpha, reused in beta

#define BAR() asm volatile("s_barrier" ::: "memory")
#define WAIT_LGKM0() asm volatile("s_waitcnt lgkmcnt(0)" ::: "memory")
#define WAIT_VM(N) asm volatile("s_waitcnt vmcnt(" #N ")" ::: "memory")
#define STAGE_A(BUF, H, S, KO)                                              \
  async_ld16(xs + (size_t)((H) * 128 + (S) * 64) * K_TOT + (KO),            \
             smem + (BUF) * 65536 + (H) * 16384 + (S) * 8192 + tid * 16)
#define STAGE_B(BUF, H, S, KO)                                              \
  async_ld16(ws + (size_t)((H) * 128 + (S) * 64) * K_TOT + (KO),            \
             smem + (BUF) * 65536 + 32768 + (H) * 16384 + (S) * 8192 + tid * 16)
#define DSR_A(BUF, QM, II, KS)                                              \
  af[II][KS] = *(const bf16x8*)(smem + (BUF) * 65536 + aBase +              \
                                ((QM) * 4 + (II)) * 2048 + rb + ((KS) ? c1 : c0))
#define DSR_B(BUF, J, KS)                                                   \
  bf[J][KS] = *(const bf16x8*)(smem + (BUF) * 65536 + bBase +               \
                               (J) * 2048 + rb + ((KS) ? c1 : c0))

#define ALPHA(BUF, KA)                                                      \
  {                                                                         \
    STAGE_A((BUF) ^ 1, 0, 0, KA); STAGE_A((BUF) ^ 1, 0, 1, KA);             \
    STAGE_A((BUF) ^ 1, 1, 0, KA); STAGE_A((BUF) ^ 1, 1, 1, KA);             \
    DSR_B(BUF, 0, 0); DSR_B(BUF, 1, 0);                                     \
    DSR_A(BUF, 0, 0, 0); DSR_A(BUF, 0, 1, 0);                               \
    DSR_B(BUF, 2, 0); DSR_B(BUF, 3, 0);                                     \
    DSR_A(BUF, 0, 2, 0); DSR_A(BUF, 0, 3, 0);                               \
    DSR_B(BUF, 0, 1); DSR_B(BUF, 1, 1);                                     \
    DSR_A(BUF, 0, 0, 1); DSR_A(BUF, 0, 1, 1);                               \
    DSR_B(BUF, 2, 1); DSR_B(BUF, 3, 1);                                     \
    DSR_A(BUF, 0, 2, 1); DSR_A(BUF, 0, 3, 1);                               \
    __builtin_amdgcn_s_setprio(1);                                          \
    mfma_half<0>(acc, af, bf);                                              \
    __builtin_amdgcn_s_setprio(0);                                          \
    WAIT_LGKM0(); BAR();                                                    \
  }

#define BETA(BUF, KB)                                                       \
  {                                                                         \
    STAGE_B(BUF, 0, 0, KB); STAGE_B(BUF, 0, 1, KB);                         \
    STAGE_B(BUF, 1, 0, KB); STAGE_B(BUF, 1, 1, KB);                         \
    DSR_A(BUF, 1, 0, 0); DSR_A(BUF, 1, 1, 0);                               \
    DSR_A(BUF, 1, 2, 0); DSR_A(BUF, 1, 3, 0);                               \
    DSR_A(BUF, 1, 0, 1); DSR_A(BUF, 1, 1, 1);                               \
    DSR_A(BUF, 1, 2, 1); DSR_A(BUF, 1, 3, 1);                               \
    __builtin_amdgcn_s_setprio(1);                                          \
    mfma_half<1>(acc, af, bf);                                              \
    __builtin_amdgcn_s_setprio(0);                                          \
    WAIT_LGKM0(); WAIT_VM(4); BAR();                                        \
  }

  // prologue: tile0 A+B -> buf0, tile1 B -> buf1; drain once.
  STAGE_A(0, 0, 0, 0); STAGE_A(0, 0, 1, 0);
  STAGE_A(0, 1, 0, 0); STAGE_A(0, 1, 1, 0);
  STAGE_B(0, 0, 0, 0); STAGE_B(0, 0, 1, 0);
  STAGE_B(0, 1, 0, 0); STAGE_B(0, 1, 1, 0);
  STAGE_B(1, 0, 0, 64); STAGE_B(1, 0, 1, 64);
  STAGE_B(1, 1, 0, 64); STAGE_B(1, 1, 1, 64);
  WAIT_VM(0);
  BAR();

  // 64 K-tiles, 2 per iteration. Tail stages (&63 wrap) are never read.
  for (int kt = 0; kt < 64; kt += 2) {
    const int ka0 = ((kt + 1) & 63) * 64;   // A of tile kt+1 -> buf1
    const int kb0 = ((kt + 2) & 63) * 64;   // B of tile kt+2 -> buf0
    const int ka1 = ((kt + 2) & 63) * 64;   // A of tile kt+2 -> buf0
    const int kb1 = ((kt + 3) & 63) * 64;   // B of tile kt+3 -> buf1
    ALPHA(0, ka0); BETA(0, kb0);
    ALPHA(1, ka1); BETA(1, kb1);
  }
  WAIT_VM(0);   // drain tail stages before workgroup exit

  // epilogue: C(i,j,r): row = bM+wm*128+i*16+(lane>>4)*4+r, col = bN+wn*64+j*16+(lane&15)
  const int row0 = bM + wm * 128 + ((lane >> 4) << 2);
  const int col0 = bN + wn * 64 + (lane & 15);
#pragma unroll
  for (int i = 0; i < 8; ++i) {
#pragma unroll
    for (int j = 0; j < 4; ++j) {
#pragma unroll
      for (int r = 0; r < 4; ++r) {
        out[(size_t)(row0 + i * 16 + r) * N_TOT + (col0 + j * 16)] = acc[i][j][r];
      }
    }
  }
#undef BAR
#undef WAIT_LGKM0
#undef WAIT_VM
#undef STAGE_A
#undef STAGE_B
#undef DSR_A
#undef DSR_B
#undef ALPHA
#undef BETA
}

extern "C" void kernel_launch(void* const* d_in, const int* in_sizes, int n_in,
                              void* d_out, int out_size, void* d_ws, size_t ws_size,
                              hipStream_t stream) {
  const float* x      = (const float*)d_in[0];   // [4,2048,4096] fp32
  const int*   wq     = (const int*)d_in[1];     // [4096,4096] int
  const float* wscale = (const float*)d_in[2];   // [1] fp32
  const float* lora_A = (const float*)d_in[3];   // [64,4096] fp32
  const float* lora_B = (const float*)d_in[4];   // [4096,64] fp32
  float* out = (float*)d_out;

  unsigned short* xb   = (unsigned short*)d_ws;
  unsigned short* weff = (unsigned short*)((char*)d_ws + (size_t)M_TOT * K_TOT * 2);

  cvt_x_kernel<<<16384, 256, 0, stream>>>((const float4*)x, (ushort8v*)xb);
  build_weff_kernel<<<dim3(K_TOT / 128, N_TOT / 128), 256, 0, stream>>>(
      wq, wscale, lora_A, lora_B, weff);
  gemm_kernel<<<512, 512, 0, stream>>>(xb, weff, out);
}